// Round 3
// baseline (394.741 us; speedup 1.0000x reference)
//
#include <hip/hip_runtime.h>
#include <cstdint>
#include <cstddef>

#define D_MODEL 1024
#define N_EXPERTS 8
#define FFN_H 2048
#define N_TOK 4096
#define CAP 2048

typedef float f32x4 __attribute__((ext_vector_type(4)));
typedef __bf16 bf16x8 __attribute__((ext_vector_type(8)));

// ---- workspace layout (bytes) ----
static constexpr size_t XB_OFF   = 0;                                                  // [N][D] bf16
static constexpr size_t HBUF_OFF = XB_OFF + (size_t)N_TOK * D_MODEL * 2;               // [E][CAP][H] bf16
static constexpr size_t CNT_OFF  = HBUF_OFF + (size_t)N_EXPERTS * CAP * FFN_H * 2;     // [8] int
static constexpr size_t PSUM_OFF = CNT_OFF + 32;                                       // [8] float
static constexpr size_t TOK_OFF  = PSUM_OFF + 32;                                      // [E][CAP] int
static constexpr size_t WGT_OFF  = TOK_OFF + (size_t)N_EXPERTS * CAP * 4;              // [E][CAP] float

// async global->LDS, 16 B per lane; LDS dest = wave-uniform base + lane*16
__device__ __forceinline__ void async_ld16(const void* g, void* l) {
    __builtin_amdgcn_global_load_lds(
        (const __attribute__((address_space(1))) unsigned int*)g,
        (__attribute__((address_space(3))) unsigned int*)l, 16, 0, 0);
}

__device__ __forceinline__ bf16x8 cvt8(float4 lo, float4 hi) {
    bf16x8 r;
    r[0] = (__bf16)lo.x; r[1] = (__bf16)lo.y; r[2] = (__bf16)lo.z; r[3] = (__bf16)lo.w;
    r[4] = (__bf16)hi.x; r[5] = (__bf16)hi.y; r[6] = (__bf16)hi.z; r[7] = (__bf16)hi.w;
    return r;
}

// ---------------- prep: blocks 0..63 = router; 64..2111 = x fp32->bf16 cvt + out zero ----------------
__global__ __launch_bounds__(256) void prep_kernel(const float* __restrict__ x,
                                                   const float* __restrict__ rw,
                                                   __bf16* __restrict__ xb,
                                                   int* __restrict__ counts,
                                                   float* __restrict__ psum,
                                                   int* __restrict__ tok_list,
                                                   float* __restrict__ wgt_list,
                                                   float* __restrict__ out) {
    __shared__ float rws[N_EXPERTS * D_MODEL];   // 32 KB (router blocks only)
    __shared__ int s_e0[64], s_e1[64], s_r0[64], s_r1[64];
    __shared__ float s_w0[64], s_w1[64];
    __shared__ int hist[8], base[8];
    __shared__ float pacc[8];

    int tid = threadIdx.x;
    int b = blockIdx.x;
    if (b >= 64) {
        // ---- x conversion + out zeroing (same 2048-float-per-block index space) ----
        int c = b - 64;
        size_t i = (size_t)c * 2048 + (size_t)tid * 8;
        float4 a = *reinterpret_cast<const float4*>(x + i);
        float4 d = *reinterpret_cast<const float4*>(x + i + 4);
        bf16x8 r;
        r[0] = (__bf16)a.x; r[1] = (__bf16)a.y; r[2] = (__bf16)a.z; r[3] = (__bf16)a.w;
        r[4] = (__bf16)d.x; r[5] = (__bf16)d.y; r[6] = (__bf16)d.z; r[7] = (__bf16)d.w;
        *reinterpret_cast<bf16x8*>(xb + i) = r;
        float4 z = {0.f, 0.f, 0.f, 0.f};
        *reinterpret_cast<float4*>(out + i) = z;
        *reinterpret_cast<float4*>(out + i + 4) = z;
        return;
    }

    // ---- router path: 64 tokens per block ----
    for (int i = tid * 4; i < N_EXPERTS * D_MODEL; i += 256 * 4)
        *reinterpret_cast<float4*>(&rws[i]) = *reinterpret_cast<const float4*>(&rw[i]);
    if (tid < 8) { hist[tid] = 0; pacc[tid] = 0.f; }
    __syncthreads();

    int wave = tid >> 6, lane = tid & 63;
    float psacc[8] = {};
    for (int it = 0; it < 16; ++it) {
        int li = wave * 16 + it;
        int t = b * 64 + li;
        const float* xr = x + (size_t)t * D_MODEL;
        float acc[8] = {};
#pragma unroll
        for (int i = 0; i < D_MODEL / 64; ++i) {
            float xv = xr[lane + 64 * i];
#pragma unroll
            for (int e = 0; e < 8; ++e) acc[e] += xv * rws[e * D_MODEL + lane + 64 * i];
        }
        float logit[8];
#pragma unroll
        for (int e = 0; e < 8; ++e) {
            float v = acc[e];
            for (int off = 32; off; off >>= 1) v += __shfl_xor(v, off);
            logit[e] = v;
        }
        float mx = logit[0];
#pragma unroll
        for (int e = 1; e < 8; ++e) mx = fmaxf(mx, logit[e]);
        float p[8], s = 0.f;
#pragma unroll
        for (int e = 0; e < 8; ++e) { p[e] = expf(logit[e] - mx); s += p[e]; }
        float inv = 1.f / s;
#pragma unroll
        for (int e = 0; e < 8; ++e) { p[e] *= inv; psacc[e] += p[e]; }
        int e0 = 0; float p0 = p[0];
#pragma unroll
        for (int e = 1; e < 8; ++e) if (p[e] > p0) { p0 = p[e]; e0 = e; }
        int e1 = -1; float p1 = -1.f;
#pragma unroll
        for (int e = 0; e < 8; ++e) if (e != e0 && p[e] > p1) { p1 = p[e]; e1 = e; }
        float invw = 1.f / (p0 + p1);
        if (lane == 0) {
            s_e0[li] = e0; s_e1[li] = e1;
            s_w0[li] = p0 * invw; s_w1[li] = p1 * invw;
        }
    }
    if (lane == 0)
#pragma unroll
        for (int e = 0; e < 8; ++e) atomicAdd(&pacc[e], psacc[e]);
    __syncthreads();

    if (tid < 64) {
        s_r0[tid] = atomicAdd(&hist[s_e0[tid]], 1);
        s_r1[tid] = atomicAdd(&hist[s_e1[tid]], 1);
    }
    __syncthreads();
    if (tid < 8) {
        base[tid] = atomicAdd(&counts[tid], hist[tid]);   // device-scope, 512 total
        atomicAdd(&psum[tid], pacc[tid]);
    }
    __syncthreads();
    if (tid < 64) {
        int t = b * 64 + tid;
        int e0 = s_e0[tid], e1 = s_e1[tid];
        int q0 = min(base[e0] + s_r0[tid], CAP - 1);
        int q1 = min(base[e1] + s_r1[tid], CAP - 1);
        tok_list[e0 * CAP + q0] = t;
        tok_list[e1 * CAP + q1] = t;
        wgt_list[e0 * CAP + q0] = s_w0[tid];
        wgt_list[e1 * CAP + q1] = s_w1[tid];
    }
}

// ---------------- grouped GEMM, 128x128 tile, BK=64, 2-deep double-buffer.
// A (bf16): global_load_lds, linear LDS dest + source-pre-swizzled 16B col blocks.
// B (fp32 weights): reg-staged (dwordx4 -> cvt -> ds_write_b128 at swizzled offset)
//   -> no weight pre-conversion pass needed.
// PASS1 epilogue: silu -> LDS-transpose -> bf16x8 stores to hbuf.
// PASS2 epilogue: weighted fp32 atomicAdd combine directly into out (no combine kernel).
// LDS map (65536 B): A ring [2][2][64 rows... ] = 2 buf x 16 KB at 0; B same at 32768.
//   chunk(buf,kk) = buf*16384 + kk*8192, layout [128][32] bf16 row-major,
//   col-block cb (16 B) stored at cb ^ ((row>>1)&3).
template <int KDIM, bool PASS2>
__global__ __launch_bounds__(256, 2) void ffn_kernel(const __bf16* __restrict__ A_base,
                                                     const float* __restrict__ B_base,
                                                     const float* __restrict__ bias,
                                                     const int* __restrict__ counts,
                                                     const int* __restrict__ tok_list,
                                                     const float* __restrict__ wgt_list,
                                                     const float* __restrict__ psum,
                                                     __bf16* __restrict__ HOut,
                                                     float* __restrict__ FOut) {
    constexpr int BROWS = PASS2 ? D_MODEL : FFN_H;
    constexpr int NT = BROWS / 128;
    constexpr int NSTEP = KDIM / 64;
    int bid = blockIdx.x;
    int tid = threadIdx.x;

    if (PASS2 && bid == 0 && tid == 0) {
        // aux load-balancing loss (counts/psum final since prep completed)
        float s = 0.f;
#pragma unroll
        for (int e = 0; e < 8; ++e)
            s += ((float)counts[e] / (float)(N_TOK * 2)) * (psum[e] / (float)N_TOK);
        FOut[(size_t)N_TOK * D_MODEL] = 8.f * s;
    }

    int e = bid & 7;                 // expert fastest -> XCD-pinned weights
    int r = bid >> 3;
    int n0 = (r % NT) * 128;
    int m0 = (r / NT) * 128;
    int cnt = min(counts[e], CAP);
    if (m0 >= cnt) return;

    __shared__ char smem[65536];

    int* s_tok = (int*)smem;
    if (!PASS2 && tid < 128) {
        int slot = min(m0 + tid, cnt - 1);
        s_tok[tid] = tok_list[e * CAP + slot];
    }
    __syncthreads();

    // ---- A staging source (bf16, global_load_lds): pre-swizzled 16B col block ----
    int colk = ((tid & 3) ^ ((tid >> 3) & 3)) * 8;
    const __bf16 *a_src0, *a_src1;
    if (PASS2) {
        int s0 = min(m0 + (tid >> 2), cnt - 1);
        int s1 = min(m0 + 64 + (tid >> 2), cnt - 1);
        a_src0 = A_base + ((size_t)e * CAP + s0) * KDIM + colk;
        a_src1 = A_base + ((size_t)e * CAP + s1) * KDIM + colk;
    } else {
        a_src0 = A_base + (size_t)s_tok[tid >> 2] * KDIM + colk;
        a_src1 = A_base + (size_t)s_tok[64 + (tid >> 2)] * KDIM + colk;
    }
    __syncthreads();   // s_tok consumed; smem reusable

    // ---- B staging source (fp32 weights, reg-staged): natural cols, swizzled ds_write ----
    const float* w_src0 = B_base + ((size_t)e * BROWS + n0 + (tid >> 2)) * KDIM + (tid & 3) * 8;
    const float* w_src1 = w_src0 + (size_t)64 * KDIM;
    int swzcb  = ((tid & 3) ^ ((tid >> 3) & 3)) * 16;        // swizzled col-block byte offset
    int wr_off0 = (tid >> 2) * 64 + swzcb;                   // rows 0-63
    int wr_off1 = wr_off0 + 4096;                            // rows 64-127

    int wv = tid >> 6, lane = tid & 63;
    int wm = wv >> 1, wn = wv & 1;
    int lm = lane & 15, q = lane >> 4;
    int rsw = (q ^ ((lm >> 1) & 3)) * 8;                     // read-side swizzle (same involution)
    int a_base = (wm * 64 + lm) * 32 + rsw;
    int b_base = (wn * 64 + lm) * 32 + rsw;
    int wofs = (tid >> 6) * 1024;

    float bv[4];
    {
        int nb = e * BROWS + n0 + wn * 64 + lm;
#pragma unroll
        for (int fn = 0; fn < 4; ++fn) bv[fn] = bias[nb + fn * 16];
    }

    f32x4 acc[4][4] = {};
    float4 b00, b01, b02, b03, b10, b11, b12, b13;

    auto stageA = [&](int t) {
        int k0 = t * 64;
        char* la = smem + (t & 1) * 16384 + wofs;
        async_ld16(a_src0 + k0,      la);
        async_ld16(a_src1 + k0,      la + 4096);
        async_ld16(a_src0 + k0 + 32, la + 8192);
        async_ld16(a_src1 + k0 + 32, la + 8192 + 4096);
    };
    auto loadB = [&](int t) {
        int k0 = t * 64;
        b00 = *reinterpret_cast<const float4*>(w_src0 + k0);
        b01 = *reinterpret_cast<const float4*>(w_src0 + k0 + 4);
        b02 = *reinterpret_cast<const float4*>(w_src0 + k0 + 32);
        b03 = *reinterpret_cast<const float4*>(w_src0 + k0 + 36);
        b10 = *reinterpret_cast<const float4*>(w_src1 + k0);
        b11 = *reinterpret_cast<const float4*>(w_src1 + k0 + 4);
        b12 = *reinterpret_cast<const float4*>(w_src1 + k0 + 32);
        b13 = *reinterpret_cast<const float4*>(w_src1 + k0 + 36);
    };
    auto writeB = [&](int t) {
        char* lb = smem + 32768 + (t & 1) * 16384;
        *reinterpret_cast<bf16x8*>(lb + wr_off0)        = cvt8(b00, b01);
        *reinterpret_cast<bf16x8*>(lb + 8192 + wr_off0) = cvt8(b02, b03);
        *reinterpret_cast<bf16x8*>(lb + wr_off1)        = cvt8(b10, b11);
        *reinterpret_cast<bf16x8*>(lb + 8192 + wr_off1) = cvt8(b12, b13);
    };
    auto compute = [&](int buf) {
#pragma unroll
        for (int kk = 0; kk < 2; ++kk) {
            const __bf16* pa = (const __bf16*)(smem + (buf * 2 + kk) * 8192);
            const __bf16* pb = (const __bf16*)(smem + 32768 + (buf * 2 + kk) * 8192);
            bf16x8 af[4], bfg[4];
#pragma unroll
            for (int f = 0; f < 4; ++f) {
                af[f]  = *reinterpret_cast<const bf16x8*>(&pa[a_base + f * 512]);
                bfg[f] = *reinterpret_cast<const bf16x8*>(&pb[b_base + f * 512]);
            }
#pragma unroll
            for (int fm = 0; fm < 4; ++fm)
#pragma unroll
                for (int fn = 0; fn < 4; ++fn)
                    acc[fm][fn] = __builtin_amdgcn_mfma_f32_16x16x32_bf16(af[fm], bfg[fn], acc[fm][fn], 0, 0, 0);
        }
    };

    // prologue: stage tile 0
    stageA(0); loadB(0); writeB(0);
    __syncthreads();

    for (int t = 0; t < NSTEP; ++t) {
        if (t + 1 < NSTEP) { stageA(t + 1); loadB(t + 1); }   // loads hide under compute
        compute(t & 1);
        if (t + 1 < NSTEP) writeB(t + 1);                     // write-late (T14 split)
        __syncthreads();
    }

    if (!PASS2) {
        // ---- epilogue: silu -> per-wave LDS transpose -> 16 B/lane coalesced bf16 stores ----
        __bf16* ep = (__bf16*)(smem) + wv * (64 * 72);
#pragma unroll
        for (int fn = 0; fn < 4; ++fn) {
#pragma unroll
            for (int fm = 0; fm < 4; ++fm)
#pragma unroll
                for (int i = 0; i < 4; ++i) {
                    float v = acc[fm][fn][i] + bv[fn];
                    v = v / (1.f + __expf(-v));
                    ep[(fm * 16 + q * 4 + i) * 72 + fn * 16 + lm] = (__bf16)v;
                }
        }
        __syncthreads();
        int rr = lane >> 3, ccol = (lane & 7) * 8;
#pragma unroll
        for (int rep = 0; rep < 8; ++rep) {
            int rw = rep * 8 + rr;
            int slot = m0 + wm * 64 + rw;
            bf16x8 vv = *reinterpret_cast<const bf16x8*>(&ep[rw * 72 + ccol]);
            if (slot < cnt)
                *reinterpret_cast<bf16x8*>(
                    &HOut[((size_t)e * CAP + slot) * FFN_H + n0 + wn * 64 + ccol]) = vv;
        }
    } else {
        // ---- epilogue: weighted fp32 atomicAdd combine into out ----
#pragma unroll
        for (int fm = 0; fm < 4; ++fm)
#pragma unroll
            for (int i = 0; i < 4; ++i) {
                int slot = m0 + wm * 64 + fm * 16 + q * 4 + i;
                if (slot < cnt) {
                    int tok = tok_list[e * CAP + slot];
                    float w = wgt_list[e * CAP + slot];
                    float* op = FOut + (size_t)tok * D_MODEL + n0 + wn * 64 + lm;
#pragma unroll
                    for (int fn = 0; fn < 4; ++fn)
                        atomicAdd(op + fn * 16, w * (acc[fm][fn][i] + bv[fn]));
                }
            }
    }
}

extern "C" void kernel_launch(void* const* d_in, const int* in_sizes, int n_in,
                              void* d_out, int out_size, void* d_ws, size_t ws_size,
                              hipStream_t stream) {
    const float* x  = (const float*)d_in[0];
    const float* rw = (const float*)d_in[1];
    const float* w1 = (const float*)d_in[2];
    const float* b1 = (const float*)d_in[3];
    const float* w2 = (const float*)d_in[4];
    const float* b2 = (const float*)d_in[5];
    float* out = (float*)d_out;

    char* ws = (char*)d_ws;
    __bf16* xb     = (__bf16*)(ws + XB_OFF);
    __bf16* hbuf   = (__bf16*)(ws + HBUF_OFF);
    int*    counts = (int*)(ws + CNT_OFF);
    float*  psum   = (float*)(ws + PSUM_OFF);
    int*    tok    = (int*)(ws + TOK_OFF);
    float*  wgt    = (float*)(ws + WGT_OFF);

    hipMemsetAsync(ws + CNT_OFF, 0, 64, stream);   // counts + psum

    prep_kernel<<<64 + 2048, 256, 0, stream>>>(x, rw, xb, counts, psum, tok, wgt, out);

    ffn_kernel<D_MODEL, false><<<8 * (FFN_H / 128) * (CAP / 128), 256, 0, stream>>>(
        xb, w1, b1, counts, tok, nullptr, nullptr, hbuf, nullptr);
    ffn_kernel<FFN_H, true><<<8 * (D_MODEL / 128) * (CAP / 128), 256, 0, stream>>>(
        hbuf, w2, b2, counts, tok, wgt, psum, nullptr, out);
}

// Round 4
// 284.494 us; speedup vs baseline: 1.3875x; 1.3875x over previous
//
#include <hip/hip_runtime.h>
#include <cstdint>
#include <cstddef>

#define D_MODEL 1024
#define N_EXPERTS 8
#define FFN_H 2048
#define N_TOK 4096
#define CAP 2048

typedef float f32x4 __attribute__((ext_vector_type(4)));
typedef __bf16 bf16x8 __attribute__((ext_vector_type(8)));

// ---- workspace layout (bytes) ----
static constexpr size_t XB_OFF   = 0;                                                  // [N][D] bf16
static constexpr size_t W1B_OFF  = XB_OFF  + (size_t)N_TOK * D_MODEL * 2;
static constexpr size_t W2B_OFF  = W1B_OFF + (size_t)N_EXPERTS * FFN_H * D_MODEL * 2;
static constexpr size_t HBUF_OFF = W2B_OFF + (size_t)N_EXPERTS * D_MODEL * FFN_H * 2;  // [E][CAP][H] bf16
static constexpr size_t YBUF_OFF = HBUF_OFF + (size_t)N_EXPERTS * CAP * FFN_H * 2;     // [E][CAP][D] bf16
static constexpr size_t CNT_OFF  = YBUF_OFF + (size_t)N_EXPERTS * CAP * D_MODEL * 2;   // [8] int
static constexpr size_t PSUM_OFF = CNT_OFF + 32;                                       // [8] float
static constexpr size_t TOK_OFF  = PSUM_OFF + 32;                                      // [E][CAP] int
static constexpr size_t TIX_OFF  = TOK_OFF + (size_t)N_EXPERTS * CAP * 4;              // [N] int2
static constexpr size_t TIW_OFF  = TIX_OFF + (size_t)N_TOK * 8;                        // [N] float2

// async global->LDS, 16 B per lane; LDS dest = wave-uniform base + lane*16
__device__ __forceinline__ void async_ld16(const void* g, void* l) {
    __builtin_amdgcn_global_load_lds(
        (const __attribute__((address_space(1))) unsigned int*)g,
        (__attribute__((address_space(3))) unsigned int*)l, 16, 0, 0);
}

__device__ __forceinline__ void cvt_block(const float* __restrict__ src,
                                          __bf16* __restrict__ dst,
                                          int c, int tid) {
    size_t i = (size_t)c * 2048 + (size_t)tid * 8;
    float4 a = *reinterpret_cast<const float4*>(src + i);
    float4 d = *reinterpret_cast<const float4*>(src + i + 4);
    bf16x8 r;
    r[0] = (__bf16)a.x; r[1] = (__bf16)a.y; r[2] = (__bf16)a.z; r[3] = (__bf16)a.w;
    r[4] = (__bf16)d.x; r[5] = (__bf16)d.y; r[6] = (__bf16)d.z; r[7] = (__bf16)d.w;
    *reinterpret_cast<bf16x8*>(dst + i) = r;
}

// ---------------- prep: blocks 0..63 = router; 64..2111 = x cvt; 2112.. = w1 cvt ----------------
__global__ __launch_bounds__(256) void prep_kernel(const float* __restrict__ x,
                                                   const float* __restrict__ rw,
                                                   const float* __restrict__ w1,
                                                   __bf16* __restrict__ xb,
                                                   __bf16* __restrict__ w1b,
                                                   int* __restrict__ counts,
                                                   float* __restrict__ psum,
                                                   int* __restrict__ tok_list,
                                                   int2* __restrict__ tinfo_idx,
                                                   float2* __restrict__ tinfo_w) {
    __shared__ float rws[N_EXPERTS * D_MODEL];   // 32 KB (router blocks only)
    __shared__ int s_e0[64], s_e1[64], s_r0[64], s_r1[64];
    __shared__ float s_w0[64], s_w1[64];
    __shared__ int hist[8], base[8];
    __shared__ float pacc[8];

    int tid = threadIdx.x;
    int b = blockIdx.x;
    if (b >= 64) {
        int c = b - 64;
        if (c < 2048) cvt_block(x, xb, c, tid);
        else          cvt_block(w1, w1b, c - 2048, tid);
        return;
    }

    // ---- router path: 64 tokens per block ----
    for (int i = tid * 4; i < N_EXPERTS * D_MODEL; i += 256 * 4)
        *reinterpret_cast<float4*>(&rws[i]) = *reinterpret_cast<const float4*>(&rw[i]);
    if (tid < 8) { hist[tid] = 0; pacc[tid] = 0.f; }
    __syncthreads();

    int wave = tid >> 6, lane = tid & 63;
    float psacc[8] = {};
    for (int it = 0; it < 16; ++it) {
        int li = wave * 16 + it;
        int t = b * 64 + li;
        const float* xr = x + (size_t)t * D_MODEL;
        float acc[8] = {};
#pragma unroll
        for (int i = 0; i < D_MODEL / 64; ++i) {
            float xv = xr[lane + 64 * i];
#pragma unroll
            for (int e = 0; e < 8; ++e) acc[e] += xv * rws[e * D_MODEL + lane + 64 * i];
        }
        float logit[8];
#pragma unroll
        for (int e = 0; e < 8; ++e) {
            float v = acc[e];
            for (int off = 32; off; off >>= 1) v += __shfl_xor(v, off);
            logit[e] = v;
        }
        float mx = logit[0];
#pragma unroll
        for (int e = 1; e < 8; ++e) mx = fmaxf(mx, logit[e]);
        float p[8], s = 0.f;
#pragma unroll
        for (int e = 0; e < 8; ++e) { p[e] = expf(logit[e] - mx); s += p[e]; }
        float inv = 1.f / s;
#pragma unroll
        for (int e = 0; e < 8; ++e) { p[e] *= inv; psacc[e] += p[e]; }
        int e0 = 0; float p0 = p[0];
#pragma unroll
        for (int e = 1; e < 8; ++e) if (p[e] > p0) { p0 = p[e]; e0 = e; }
        int e1 = -1; float p1 = -1.f;
#pragma unroll
        for (int e = 0; e < 8; ++e) if (e != e0 && p[e] > p1) { p1 = p[e]; e1 = e; }
        float invw = 1.f / (p0 + p1);
        if (lane == 0) {
            s_e0[li] = e0; s_e1[li] = e1;
            s_w0[li] = p0 * invw; s_w1[li] = p1 * invw;
        }
    }
    if (lane == 0)
#pragma unroll
        for (int e = 0; e < 8; ++e) atomicAdd(&pacc[e], psacc[e]);
    __syncthreads();

    if (tid < 64) {
        s_r0[tid] = atomicAdd(&hist[s_e0[tid]], 1);
        s_r1[tid] = atomicAdd(&hist[s_e1[tid]], 1);
    }
    __syncthreads();
    if (tid < 8) {
        base[tid] = atomicAdd(&counts[tid], hist[tid]);   // device-scope, 512 total
        atomicAdd(&psum[tid], pacc[tid]);
    }
    __syncthreads();
    if (tid < 64) {
        int t = b * 64 + tid;
        int e0 = s_e0[tid], e1 = s_e1[tid];
        int q0 = min(base[e0] + s_r0[tid], CAP - 1);
        int q1 = min(base[e1] + s_r1[tid], CAP - 1);
        tok_list[e0 * CAP + q0] = t;
        tok_list[e1 * CAP + q1] = t;
        tinfo_idx[t] = make_int2(e0 * CAP + q0, e1 * CAP + q1);
        tinfo_w[t] = make_float2(s_w0[tid], s_w1[tid]);
    }
}

// ---------------- grouped GEMM, 128x128 tile, BK=64, double-buffered global_load_lds,
//                  both-sides bank swizzle, LDS-transpose vectorized epilogue ----------------
// CVT instantiation (pass1): blocks [ngemm..) convert the NEXT pass's weights (w2 fp32->bf16),
// weaving that traffic into this kernel's idle HBM bandwidth instead of a serial prep phase.
// LDS map (65536 B): A chunks at (dbuf*2+kk)*8192; B at 32768 + same; s_tok transient at 0;
// epilogue per-wave [64][72] bf16 at wv*9216.
template <int KDIM, bool PASS2, bool CVT>
__global__ __launch_bounds__(256, 2) void ffn_kernel(const __bf16* __restrict__ A_base,
                                                     const __bf16* __restrict__ B_base,
                                                     const float* __restrict__ bias,
                                                     const int* __restrict__ counts,
                                                     const int* __restrict__ tok_list,
                                                     __bf16* __restrict__ Out_base,
                                                     const float* __restrict__ cvt_src,
                                                     __bf16* __restrict__ cvt_dst,
                                                     int ngemm) {
    constexpr int BROWS = PASS2 ? D_MODEL : FFN_H;
    constexpr int NT = BROWS / 128;
    constexpr int NSTEP = KDIM / 64;
    int bid = blockIdx.x;
    int tid = threadIdx.x;

    if (CVT && bid >= ngemm) {          // converter blocks: fp32 -> bf16, 2048 floats each
        cvt_block(cvt_src, cvt_dst, bid - ngemm, tid);
        return;
    }

    int e = bid & 7;                 // expert fastest -> XCD-pinned weights
    int r = bid >> 3;
    int n0 = (r % NT) * 128;
    int m0 = (r / NT) * 128;
    int cnt = min(counts[e], CAP);
    if (m0 >= cnt) return;

    __shared__ char smem[65536];

    int* s_tok = (int*)smem;
    if (!PASS2 && tid < 128) {
        int slot = min(m0 + tid, cnt - 1);
        s_tok[tid] = tok_list[e * CAP + slot];
    }
    __syncthreads();

    // staging source pre-swizzle: 16-B col block XOR'd with ((row>>1)&3); LDS dest linear
    int colk = ((tid & 3) ^ ((tid >> 3) & 3)) * 8;
    const __bf16 *a_src0, *a_src1;
    if (PASS2) {
        int s0 = min(m0 + (tid >> 2), cnt - 1);
        int s1 = min(m0 + 64 + (tid >> 2), cnt - 1);
        a_src0 = A_base + ((size_t)e * CAP + s0) * KDIM + colk;
        a_src1 = A_base + ((size_t)e * CAP + s1) * KDIM + colk;
    } else {
        a_src0 = A_base + (size_t)s_tok[tid >> 2] * KDIM + colk;
        a_src1 = A_base + (size_t)s_tok[64 + (tid >> 2)] * KDIM + colk;
    }
    const __bf16* b_src0 = B_base + ((size_t)e * BROWS + n0 + (tid >> 2)) * KDIM + colk;
    const __bf16* b_src1 = b_src0 + (size_t)64 * KDIM;
    __syncthreads();   // s_tok consumed; smem reusable for staging

    int wv = tid >> 6, lane = tid & 63;
    int wm = wv >> 1, wn = wv & 1;
    int lm = lane & 15, q = lane >> 4;
    // read-side swizzle matches the source pre-swizzle (same involution)
    int rsw = (q ^ ((lm >> 1) & 3)) * 8;
    int a_base = (wm * 64 + lm) * 32 + rsw;
    int b_base = (wn * 64 + lm) * 32 + rsw;

    char* wofs_a = smem + (tid >> 6) * 1024;
    char* wofs_b = smem + 32768 + (tid >> 6) * 1024;

    f32x4 acc[4][4] = {};

    // prologue: stage tile 0 into buffer 0
    {
        char* la = wofs_a; char* lb = wofs_b;
        async_ld16(a_src0,      la);        async_ld16(a_src1,      la + 4096);
        async_ld16(a_src0 + 32, la + 8192); async_ld16(a_src1 + 32, la + 8192 + 4096);
        async_ld16(b_src0,      lb);        async_ld16(b_src1,      lb + 4096);
        async_ld16(b_src0 + 32, lb + 8192); async_ld16(b_src1 + 32, lb + 8192 + 4096);
    }
    __syncthreads();

    int cur = 0;
    for (int t = 0; t < NSTEP; ++t) {
        if (t + 1 < NSTEP) {
            int k0 = (t + 1) * 64;
            char* la = wofs_a + ((cur ^ 1) * 16384);
            char* lb = wofs_b + ((cur ^ 1) * 16384);
            async_ld16(a_src0 + k0,      la);        async_ld16(a_src1 + k0,      la + 4096);
            async_ld16(a_src0 + k0 + 32, la + 8192); async_ld16(a_src1 + k0 + 32, la + 8192 + 4096);
            async_ld16(b_src0 + k0,      lb);        async_ld16(b_src1 + k0,      lb + 4096);
            async_ld16(b_src0 + k0 + 32, lb + 8192); async_ld16(b_src1 + k0 + 32, lb + 8192 + 4096);
        }
#pragma unroll
        for (int kk = 0; kk < 2; ++kk) {
            const __bf16* pa = (const __bf16*)(smem + (cur * 2 + kk) * 8192);
            const __bf16* pb = (const __bf16*)(smem + 32768 + (cur * 2 + kk) * 8192);
            bf16x8 af[4], bfg[4];
#pragma unroll
            for (int f = 0; f < 4; ++f) {
                af[f]  = *reinterpret_cast<const bf16x8*>(&pa[a_base + f * 512]);
                bfg[f] = *reinterpret_cast<const bf16x8*>(&pb[b_base + f * 512]);
            }
#pragma unroll
            for (int fm = 0; fm < 4; ++fm)
#pragma unroll
                for (int fn = 0; fn < 4; ++fn)
                    acc[fm][fn] = __builtin_amdgcn_mfma_f32_16x16x32_bf16(af[fm], bfg[fn], acc[fm][fn], 0, 0, 0);
        }
        __syncthreads();   // drains vmcnt+lgkmcnt: next tile landed, cur fully read
        cur ^= 1;
    }

    // ---- epilogue: per-wave LDS transpose -> 16 B/lane coalesced stores ----
    // [64][72] bf16 per wave: row stride 144 B (16-B aligned, 2-way max both phases)
    __bf16* ep = (__bf16*)(smem) + wv * (64 * 72);
#pragma unroll
    for (int fn = 0; fn < 4; ++fn) {
        int n = n0 + wn * 64 + fn * 16 + lm;
        float bv = bias[e * BROWS + n];
#pragma unroll
        for (int fm = 0; fm < 4; ++fm)
#pragma unroll
            for (int i = 0; i < 4; ++i) {
                float v = acc[fm][fn][i] + bv;
                if (!PASS2) v = v / (1.f + __expf(-v));
                ep[(fm * 16 + q * 4 + i) * 72 + fn * 16 + lm] = (__bf16)v;
            }
    }
    __syncthreads();
    int rr = lane >> 3, ccol = (lane & 7) * 8;
#pragma unroll
    for (int rep = 0; rep < 8; ++rep) {
        int rw = rep * 8 + rr;
        int slot = m0 + wm * 64 + rw;
        bf16x8 vv = *reinterpret_cast<const bf16x8*>(&ep[rw * 72 + ccol]);
        if (slot < cnt)
            *reinterpret_cast<bf16x8*>(
                &Out_base[((size_t)e * CAP + slot) * BROWS + n0 + wn * 64 + ccol]) = vv;
    }
}

// ---------------- combine: out[t] = w0*y[idx0] + w1*y[idx1]; block 0 thread 0 does aux ----------------
__global__ __launch_bounds__(256) void combine_kernel(const __bf16* __restrict__ ybuf,
                                                      const int2* __restrict__ tinfo_idx,
                                                      const float2* __restrict__ tinfo_w,
                                                      const int* __restrict__ counts,
                                                      const float* __restrict__ psum,
                                                      float* __restrict__ out) {
    int tid = threadIdx.x;
    if (blockIdx.x == 0 && tid == 0) {
        float s = 0.f;
#pragma unroll
        for (int e = 0; e < 8; ++e)
            s += ((float)counts[e] / (float)(N_TOK * 2)) * (psum[e] / (float)N_TOK);
        out[(size_t)N_TOK * D_MODEL] = 8.f * s;
    }
    int t = blockIdx.x * 2 + (tid >> 7);
    int d0 = (tid & 127) * 8;
    int2 ix = tinfo_idx[t];
    float2 w = tinfo_w[t];
    bf16x8 ya = *reinterpret_cast<const bf16x8*>(ybuf + (size_t)ix.x * D_MODEL + d0);
    bf16x8 yb = *reinterpret_cast<const bf16x8*>(ybuf + (size_t)ix.y * D_MODEL + d0);
    float4 o0, o1;
    o0.x = w.x * (float)ya[0] + w.y * (float)yb[0];
    o0.y = w.x * (float)ya[1] + w.y * (float)yb[1];
    o0.z = w.x * (float)ya[2] + w.y * (float)yb[2];
    o0.w = w.x * (float)ya[3] + w.y * (float)yb[3];
    o1.x = w.x * (float)ya[4] + w.y * (float)yb[4];
    o1.y = w.x * (float)ya[5] + w.y * (float)yb[5];
    o1.z = w.x * (float)ya[6] + w.y * (float)yb[6];
    o1.w = w.x * (float)ya[7] + w.y * (float)yb[7];
    float* op = out + (size_t)t * D_MODEL + d0;
    *reinterpret_cast<float4*>(op) = o0;
    *reinterpret_cast<float4*>(op + 4) = o1;
}

extern "C" void kernel_launch(void* const* d_in, const int* in_sizes, int n_in,
                              void* d_out, int out_size, void* d_ws, size_t ws_size,
                              hipStream_t stream) {
    const float* x  = (const float*)d_in[0];
    const float* rw = (const float*)d_in[1];
    const float* w1 = (const float*)d_in[2];
    const float* b1 = (const float*)d_in[3];
    const float* w2 = (const float*)d_in[4];
    const float* b2 = (const float*)d_in[5];
    float* out = (float*)d_out;

    char* ws = (char*)d_ws;
    __bf16* xb     = (__bf16*)(ws + XB_OFF);
    __bf16* w1b    = (__bf16*)(ws + W1B_OFF);
    __bf16* w2b    = (__bf16*)(ws + W2B_OFF);
    __bf16* hbuf   = (__bf16*)(ws + HBUF_OFF);
    __bf16* ybuf   = (__bf16*)(ws + YBUF_OFF);
    int*    counts = (int*)(ws + CNT_OFF);
    float*  psum   = (float*)(ws + PSUM_OFF);
    int*    tok    = (int*)(ws + TOK_OFF);
    int2*   tix    = (int2*)(ws + TIX_OFF);
    float2* tiw    = (float2*)(ws + TIW_OFF);

    hipMemsetAsync(ws + CNT_OFF, 0, 64, stream);   // counts + psum

    // prep: router (64) + x cvt (2048) + w1 cvt (8192)
    prep_kernel<<<64 + 2048 + 8192, 256, 0, stream>>>(x, rw, w1, xb, w1b,
                                                      counts, psum, tok, tix, tiw);

    // pass1 GEMM (2048 blocks) + w2 fp32->bf16 converters (8192 blocks)
    constexpr int NG1 = 8 * (FFN_H / 128) * (CAP / 128);
    ffn_kernel<D_MODEL, false, true><<<NG1 + 8192, 256, 0, stream>>>(
        xb, w1b, b1, counts, tok, hbuf, w2, w2b, NG1);

    constexpr int NG2 = 8 * (D_MODEL / 128) * (CAP / 128);
    ffn_kernel<FFN_H, true, false><<<NG2, 256, 0, stream>>>(
        hbuf, w2b, b2, counts, tok, ybuf, nullptr, nullptr, NG2);

    combine_kernel<<<N_TOK / 2, 256, 0, stream>>>(ybuf, tix, tiw, counts, psum, out);
}

// Round 5
// 283.933 us; speedup vs baseline: 1.3903x; 1.0020x over previous
//
#include <hip/hip_runtime.h>
#include <cstdint>
#include <cstddef>

#define D_MODEL 1024
#define N_EXPERTS 8
#define FFN_H 2048
#define N_TOK 4096
#define CAP 2048

typedef float f32x4 __attribute__((ext_vector_type(4)));
typedef __bf16 bf16x8 __attribute__((ext_vector_type(8)));

// ---- workspace layout (bytes) ----
static constexpr size_t XB_OFF   = 0;                                                  // [N][D] bf16
static constexpr size_t W1B_OFF  = XB_OFF  + (size_t)N_TOK * D_MODEL * 2;
static constexpr size_t W2B_OFF  = W1B_OFF + (size_t)N_EXPERTS * FFN_H * D_MODEL * 2;
static constexpr size_t HBUF_OFF = W2B_OFF + (size_t)N_EXPERTS * D_MODEL * FFN_H * 2;  // [E][CAP][H] bf16
static constexpr size_t YBUF_OFF = HBUF_OFF + (size_t)N_EXPERTS * CAP * FFN_H * 2;     // [E][CAP][D] bf16
static constexpr size_t CNT_OFF  = YBUF_OFF + (size_t)N_EXPERTS * CAP * D_MODEL * 2;   // [8] int
static constexpr size_t PSUM_OFF = CNT_OFF + 32;                                       // [8] float
static constexpr size_t TOK_OFF  = PSUM_OFF + 32;                                      // [E][CAP] int
static constexpr size_t TIX_OFF  = TOK_OFF + (size_t)N_EXPERTS * CAP * 4;              // [N] int2
static constexpr size_t TIW_OFF  = TIX_OFF + (size_t)N_TOK * 8;                        // [N] float2

// async global->LDS, 16 B per lane; LDS dest = wave-uniform base + lane*16
__device__ __forceinline__ void async_ld16(const void* g, void* l) {
    __builtin_amdgcn_global_load_lds(
        (const __attribute__((address_space(1))) unsigned int*)g,
        (__attribute__((address_space(3))) unsigned int*)l, 16, 0, 0);
}

__device__ __forceinline__ void cvt_block(const float* __restrict__ src,
                                          __bf16* __restrict__ dst,
                                          int c, int tid) {
    size_t i = (size_t)c * 2048 + (size_t)tid * 8;
    float4 a = *reinterpret_cast<const float4*>(src + i);
    float4 d = *reinterpret_cast<const float4*>(src + i + 4);
    bf16x8 r;
    r[0] = (__bf16)a.x; r[1] = (__bf16)a.y; r[2] = (__bf16)a.z; r[3] = (__bf16)a.w;
    r[4] = (__bf16)d.x; r[5] = (__bf16)d.y; r[6] = (__bf16)d.z; r[7] = (__bf16)d.w;
    *reinterpret_cast<bf16x8*>(dst + i) = r;
}

// ---------------- prep: blocks 0..63 = router; 64..2111 = x cvt; 2112.. = w1 cvt ----------------
__global__ __launch_bounds__(256) void prep_kernel(const float* __restrict__ x,
                                                   const float* __restrict__ rw,
                                                   const float* __restrict__ w1,
                                                   __bf16* __restrict__ xb,
                                                   __bf16* __restrict__ w1b,
                                                   int* __restrict__ counts,
                                                   float* __restrict__ psum,
                                                   int* __restrict__ tok_list,
                                                   int2* __restrict__ tinfo_idx,
                                                   float2* __restrict__ tinfo_w) {
    __shared__ float rws[N_EXPERTS * D_MODEL];   // 32 KB (router blocks only)
    __shared__ int s_e0[64], s_e1[64], s_r0[64], s_r1[64];
    __shared__ float s_w0[64], s_w1[64];
    __shared__ int hist[8], base[8];
    __shared__ float pacc[8];

    int tid = threadIdx.x;
    int b = blockIdx.x;
    if (b >= 64) {
        int c = b - 64;
        if (c < 2048) cvt_block(x, xb, c, tid);
        else          cvt_block(w1, w1b, c - 2048, tid);
        return;
    }

    // ---- router path: 64 tokens per block ----
    for (int i = tid * 4; i < N_EXPERTS * D_MODEL; i += 256 * 4)
        *reinterpret_cast<float4*>(&rws[i]) = *reinterpret_cast<const float4*>(&rw[i]);
    if (tid < 8) { hist[tid] = 0; pacc[tid] = 0.f; }
    __syncthreads();

    int wave = tid >> 6, lane = tid & 63;
    float psacc[8] = {};
    for (int it = 0; it < 16; ++it) {
        int li = wave * 16 + it;
        int t = b * 64 + li;
        const float* xr = x + (size_t)t * D_MODEL;
        float acc[8] = {};
#pragma unroll
        for (int i = 0; i < D_MODEL / 64; ++i) {
            float xv = xr[lane + 64 * i];
#pragma unroll
            for (int e = 0; e < 8; ++e) acc[e] += xv * rws[e * D_MODEL + lane + 64 * i];
        }
        float logit[8];
#pragma unroll
        for (int e = 0; e < 8; ++e) {
            float v = acc[e];
            for (int off = 32; off; off >>= 1) v += __shfl_xor(v, off);
            logit[e] = v;
        }
        float mx = logit[0];
#pragma unroll
        for (int e = 1; e < 8; ++e) mx = fmaxf(mx, logit[e]);
        float p[8], s = 0.f;
#pragma unroll
        for (int e = 0; e < 8; ++e) { p[e] = expf(logit[e] - mx); s += p[e]; }
        float inv = 1.f / s;
#pragma unroll
        for (int e = 0; e < 8; ++e) { p[e] *= inv; psacc[e] += p[e]; }
        int e0 = 0; float p0 = p[0];
#pragma unroll
        for (int e = 1; e < 8; ++e) if (p[e] > p0) { p0 = p[e]; e0 = e; }
        int e1 = -1; float p1 = -1.f;
#pragma unroll
        for (int e = 0; e < 8; ++e) if (e != e0 && p[e] > p1) { p1 = p[e]; e1 = e; }
        float invw = 1.f / (p0 + p1);
        if (lane == 0) {
            s_e0[li] = e0; s_e1[li] = e1;
            s_w0[li] = p0 * invw; s_w1[li] = p1 * invw;
        }
    }
    if (lane == 0)
#pragma unroll
        for (int e = 0; e < 8; ++e) atomicAdd(&pacc[e], psacc[e]);
    __syncthreads();

    if (tid < 64) {
        s_r0[tid] = atomicAdd(&hist[s_e0[tid]], 1);
        s_r1[tid] = atomicAdd(&hist[s_e1[tid]], 1);
    }
    __syncthreads();
    if (tid < 8) {
        base[tid] = atomicAdd(&counts[tid], hist[tid]);   // device-scope, 512 total
        atomicAdd(&psum[tid], pacc[tid]);
    }
    __syncthreads();
    if (tid < 64) {
        int t = b * 64 + tid;
        int e0 = s_e0[tid], e1 = s_e1[tid];
        int q0 = min(base[e0] + s_r0[tid], CAP - 1);
        int q1 = min(base[e1] + s_r1[tid], CAP - 1);
        tok_list[e0 * CAP + q0] = t;
        tok_list[e1 * CAP + q1] = t;
        tinfo_idx[t] = make_int2(e0 * CAP + q0, e1 * CAP + q1);
        tinfo_w[t] = make_float2(s_w0[tid], s_w1[tid]);
    }
}

// ---------------- grouped GEMM, 128x128 tile, BK=32, 2-deep double-buffer (36,864 B LDS
//                  -> 4 blocks/CU), global_load_lds, both-sides bank swizzle,
//                  LDS-transpose vectorized epilogue ----------------
// CVT instantiation (pass1): cvt blocks INTERLEAVED 4:1 with GEMM blocks (bid%5==0 -> GEMM)
// so converter traffic soaks HBM alongside the latency-bound GEMM for the whole kernel.
// Expert->XCD pinning survives: gemm_id g -> bid=5g -> XCD=(5g)%8 is a bijection on g%8.
// LDS map (36864 B): A bufs at 0/8192; B bufs at 16384/24576 ([128][32] bf16 chunks,
// col-block cb stored at cb ^ ((row>>1)&3)); epilogue overlay per-wave [64][72] at wv*9216.
template <int KDIM, bool PASS2, bool CVT>
__global__ __launch_bounds__(256, 4) void ffn_kernel(const __bf16* __restrict__ A_base,
                                                     const __bf16* __restrict__ B_base,
                                                     const float* __restrict__ bias,
                                                     const int* __restrict__ counts,
                                                     const int* __restrict__ tok_list,
                                                     __bf16* __restrict__ Out_base,
                                                     const float* __restrict__ cvt_src,
                                                     __bf16* __restrict__ cvt_dst) {
    constexpr int BROWS = PASS2 ? D_MODEL : FFN_H;
    constexpr int NT = BROWS / 128;
    constexpr int NSTEP = KDIM / 32;
    int bid = blockIdx.x;
    int tid = threadIdx.x;

    int gid;
    if (CVT) {
        int m5 = bid % 5;
        if (m5) {   // converter block: fp32 -> bf16, 2048 floats
            cvt_block(cvt_src, cvt_dst, (bid / 5) * 4 + m5 - 1, tid);
            return;
        }
        gid = bid / 5;
    } else {
        gid = bid;
    }

    int e = gid & 7;                 // expert fastest -> XCD-pinned weights
    int r = gid >> 3;
    int n0 = (r % NT) * 128;
    int m0 = (r / NT) * 128;
    int cnt = min(counts[e], CAP);
    if (m0 >= cnt) return;

    __shared__ char smem[36864];

    int* s_tok = (int*)smem;
    if (!PASS2 && tid < 128) {
        int slot = min(m0 + tid, cnt - 1);
        s_tok[tid] = tok_list[e * CAP + slot];
    }
    __syncthreads();

    // staging source pre-swizzle: 16-B col block XOR'd with ((row>>1)&3); LDS dest linear
    int colk = ((tid & 3) ^ ((tid >> 3) & 3)) * 8;
    const __bf16 *a_src0, *a_src1;
    if (PASS2) {
        int s0 = min(m0 + (tid >> 2), cnt - 1);
        int s1 = min(m0 + 64 + (tid >> 2), cnt - 1);
        a_src0 = A_base + ((size_t)e * CAP + s0) * KDIM + colk;
        a_src1 = A_base + ((size_t)e * CAP + s1) * KDIM + colk;
    } else {
        a_src0 = A_base + (size_t)s_tok[tid >> 2] * KDIM + colk;
        a_src1 = A_base + (size_t)s_tok[64 + (tid >> 2)] * KDIM + colk;
    }
    const __bf16* b_src0 = B_base + ((size_t)e * BROWS + n0 + (tid >> 2)) * KDIM + colk;
    const __bf16* b_src1 = b_src0 + (size_t)64 * KDIM;
    __syncthreads();   // s_tok consumed; smem reusable for staging

    int wv = tid >> 6, lane = tid & 63;
    int wm = wv >> 1, wn = wv & 1;
    int lm = lane & 15, q = lane >> 4;
    // read-side swizzle matches the source pre-swizzle (same involution)
    int rsw = (q ^ ((lm >> 1) & 3)) * 8;
    int a_base = (wm * 64 + lm) * 32 + rsw;
    int b_base = (wn * 64 + lm) * 32 + rsw;
    int wofs = wv * 1024;

    f32x4 acc[4][4] = {};

    auto stage = [&](int t) {
        int k0 = t * 32;
        int bo = (t & 1) * 8192;
        char* la = smem + bo + wofs;
        char* lb = smem + 16384 + bo + wofs;
        async_ld16(a_src0 + k0, la);
        async_ld16(a_src1 + k0, la + 4096);
        async_ld16(b_src0 + k0, lb);
        async_ld16(b_src1 + k0, lb + 4096);
    };
    auto compute = [&](int t) {
        int bo = (t & 1) * 8192;
        const __bf16* pa = (const __bf16*)(smem + bo);
        const __bf16* pb = (const __bf16*)(smem + 16384 + bo);
        bf16x8 af[4], bfg[4];
#pragma unroll
        for (int f = 0; f < 4; ++f) {
            af[f]  = *reinterpret_cast<const bf16x8*>(&pa[a_base + f * 512]);
            bfg[f] = *reinterpret_cast<const bf16x8*>(&pb[b_base + f * 512]);
        }
#pragma unroll
        for (int fm = 0; fm < 4; ++fm)
#pragma unroll
            for (int fn = 0; fn < 4; ++fn)
                acc[fm][fn] = __builtin_amdgcn_mfma_f32_16x16x32_bf16(af[fm], bfg[fn], acc[fm][fn], 0, 0, 0);
    };

    stage(0);
    __syncthreads();
    for (int t = 0; t < NSTEP; ++t) {
        if (t + 1 < NSTEP) stage(t + 1);   // fire-and-forget into other buffer
        compute(t);
        __syncthreads();   // drains vmcnt+lgkmcnt: next tile landed, buf t fully read
    }

    // ---- epilogue: per-wave LDS transpose -> 16 B/lane coalesced stores ----
    // [64][72] bf16 per wave: row stride 144 B (16-B aligned, 2-way max both phases)
    __bf16* ep = (__bf16*)(smem) + wv * (64 * 72);
#pragma unroll
    for (int fn = 0; fn < 4; ++fn) {
        int n = n0 + wn * 64 + fn * 16 + lm;
        float bv = bias[e * BROWS + n];
#pragma unroll
        for (int fm = 0; fm < 4; ++fm)
#pragma unroll
            for (int i = 0; i < 4; ++i) {
                float v = acc[fm][fn][i] + bv;
                if (!PASS2) v = v / (1.f + __expf(-v));
                ep[(fm * 16 + q * 4 + i) * 72 + fn * 16 + lm] = (__bf16)v;
            }
    }
    __syncthreads();
    int rr = lane >> 3, ccol = (lane & 7) * 8;
#pragma unroll
    for (int rep = 0; rep < 8; ++rep) {
        int rw = rep * 8 + rr;
        int slot = m0 + wm * 64 + rw;
        bf16x8 vv = *reinterpret_cast<const bf16x8*>(&ep[rw * 72 + ccol]);
        if (slot < cnt)
            *reinterpret_cast<bf16x8*>(
                &Out_base[((size_t)e * CAP + slot) * BROWS + n0 + wn * 64 + ccol]) = vv;
    }
}

// ---------------- combine: out[t] = w0*y[idx0] + w1*y[idx1]; block 0 thread 0 does aux ----------------
__global__ __launch_bounds__(256) void combine_kernel(const __bf16* __restrict__ ybuf,
                                                      const int2* __restrict__ tinfo_idx,
                                                      const float2* __restrict__ tinfo_w,
                                                      const int* __restrict__ counts,
                                                      const float* __restrict__ psum,
                                                      float* __restrict__ out) {
    int tid = threadIdx.x;
    if (blockIdx.x == 0 && tid == 0) {
        float s = 0.f;
#pragma unroll
        for (int e = 0; e < 8; ++e)
            s += ((float)counts[e] / (float)(N_TOK * 2)) * (psum[e] / (float)N_TOK);
        out[(size_t)N_TOK * D_MODEL] = 8.f * s;
    }
    int t = blockIdx.x * 2 + (tid >> 7);
    int d0 = (tid & 127) * 8;
    int2 ix = tinfo_idx[t];
    float2 w = tinfo_w[t];
    bf16x8 ya = *reinterpret_cast<const bf16x8*>(ybuf + (size_t)ix.x * D_MODEL + d0);
    bf16x8 yb = *reinterpret_cast<const bf16x8*>(ybuf + (size_t)ix.y * D_MODEL + d0);
    float4 o0, o1;
    o0.x = w.x * (float)ya[0] + w.y * (float)yb[0];
    o0.y = w.x * (float)ya[1] + w.y * (float)yb[1];
    o0.z = w.x * (float)ya[2] + w.y * (float)yb[2];
    o0.w = w.x * (float)ya[3] + w.y * (float)yb[3];
    o1.x = w.x * (float)ya[4] + w.y * (float)yb[4];
    o1.y = w.x * (float)ya[5] + w.y * (float)yb[5];
    o1.z = w.x * (float)ya[6] + w.y * (float)yb[6];
    o1.w = w.x * (float)ya[7] + w.y * (float)yb[7];
    float* op = out + (size_t)t * D_MODEL + d0;
    *reinterpret_cast<float4*>(op) = o0;
    *reinterpret_cast<float4*>(op + 4) = o1;
}

extern "C" void kernel_launch(void* const* d_in, const int* in_sizes, int n_in,
                              void* d_out, int out_size, void* d_ws, size_t ws_size,
                              hipStream_t stream) {
    const float* x  = (const float*)d_in[0];
    const float* rw = (const float*)d_in[1];
    const float* w1 = (const float*)d_in[2];
    const float* b1 = (const float*)d_in[3];
    const float* w2 = (const float*)d_in[4];
    const float* b2 = (const float*)d_in[5];
    float* out = (float*)d_out;

    char* ws = (char*)d_ws;
    __bf16* xb     = (__bf16*)(ws + XB_OFF);
    __bf16* w1b    = (__bf16*)(ws + W1B_OFF);
    __bf16* w2b    = (__bf16*)(ws + W2B_OFF);
    __bf16* hbuf   = (__bf16*)(ws + HBUF_OFF);
    __bf16* ybuf   = (__bf16*)(ws + YBUF_OFF);
    int*    counts = (int*)(ws + CNT_OFF);
    float*  psum   = (float*)(ws + PSUM_OFF);
    int*    tok    = (int*)(ws + TOK_OFF);
    int2*   tix    = (int2*)(ws + TIX_OFF);
    float2* tiw    = (float2*)(ws + TIW_OFF);

    hipMemsetAsync(ws + CNT_OFF, 0, 64, stream);   // counts + psum

    // prep: router (64) + x cvt (2048) + w1 cvt (8192)
    prep_kernel<<<64 + 2048 + 8192, 256, 0, stream>>>(x, rw, w1, xb, w1b,
                                                      counts, psum, tok, tix, tiw);

    // pass1: GEMM blocks (2048) interleaved 1:4 with w2 fp32->bf16 converters (8192)
    constexpr int NG1 = 8 * (FFN_H / 128) * (CAP / 128);
    ffn_kernel<D_MODEL, false, true><<<NG1 + 8192, 256, 0, stream>>>(
        xb, w1b, b1, counts, tok, hbuf, w2, w2b);

    constexpr int NG2 = 8 * (D_MODEL / 128) * (CAP / 128);
    ffn_kernel<FFN_H, true, false><<<NG2, 256, 0, stream>>>(
        hbuf, w2b, b2, counts, tok, ybuf, nullptr, nullptr);

    combine_kernel<<<N_TOK / 2, 256, 0, stream>>>(ybuf, tix, tiw, counts, psum, out);
}